// Round 4
// baseline (12329.984 us; speedup 1.0000x reference)
//
#include <hip/hip_runtime.h>
#include <math.h>

#define BATCH  65536
#define SD     256
#define AD     129
#define HID    256
#define NSTEP  30
#define EPS_LN 1e-5f
#define M      32

typedef _Float16 v8h  __attribute__((ext_vector_type(8)));
typedef _Float16 v2h  __attribute__((ext_vector_type(2)));
typedef float    v16f __attribute__((ext_vector_type(16)));

#define LOSCALE 4096.0f
#define LOINV   (1.0f/4096.0f)

// d_ws layout (bytes) — transposed, fp16-split weights. ~820 KB total.
#define T1H_OFF 0
#define T1L_OFF 212992
#define T2H_OFF 425984
#define T2L_OFF 557056
#define T3H_OFF 688128
#define T3L_OFF 753664
#define W3C_OFF 819200
#define KP1 416   // W1^T padded K (386 -> 416), zeros beyond 385
#define KP2 256
#define KP3 256

// One block per output row n: T[n][k] = W[k][n], split into hi + lo*2^-12.
__global__ __launch_bounds__(256)
void repack(const float* __restrict__ W1, const float* __restrict__ W2,
            const float* __restrict__ W3, char* __restrict__ ws)
{
    _Float16* t1h = (_Float16*)(ws + T1H_OFF);
    _Float16* t1l = (_Float16*)(ws + T1L_OFF);
    _Float16* t2h = (_Float16*)(ws + T2H_OFF);
    _Float16* t2l = (_Float16*)(ws + T2L_OFF);
    _Float16* t3h = (_Float16*)(ws + T3H_OFF);
    _Float16* t3l = (_Float16*)(ws + T3L_OFF);
    float*    w3c = (float*)(ws + W3C_OFF);
    const int n = blockIdx.x;
    for (int k = threadIdx.x; k < KP1; k += 256) {
        float v = (k < 386) ? W1[(size_t)k * HID + n] : 0.f;
        _Float16 h = (_Float16)v;
        t1h[(size_t)n * KP1 + k] = h;
        t1l[(size_t)n * KP1 + k] = (_Float16)((v - (float)h) * LOSCALE);
    }
    {
        int k = threadIdx.x;
        float v = W2[(size_t)k * HID + n];
        _Float16 h = (_Float16)v;
        t2h[(size_t)n * KP2 + k] = h;
        t2l[(size_t)n * KP2 + k] = (_Float16)((v - (float)h) * LOSCALE);
    }
    if (n < 128) {
        int k = threadIdx.x;
        float v = W3[(size_t)k * AD + n];
        _Float16 h = (_Float16)v;
        t3h[(size_t)n * KP3 + k] = h;
        t3l[(size_t)n * KP3 + k] = (_Float16)((v - (float)h) * LOSCALE);
    }
    if (n == 0) w3c[threadIdx.x] = W3[(size_t)threadIdx.x * AD + 128];
}

__device__ __forceinline__ v16f vzero() {
    v16f z;
    #pragma unroll
    for (int i = 0; i < 16; ++i) z[i] = 0.f;
    return z;
}

__device__ __forceinline__ void wave_reduce_add8(float v[8]) {
    #pragma unroll
    for (int d = 1; d < 64; d <<= 1) {
        #pragma unroll
        for (int r = 0; r < 8; ++r) v[r] += __shfl_xor(v[r], d);
    }
}
__device__ __forceinline__ void wave_reduce_max8(float v[8]) {
    #pragma unroll
    for (int d = 1; d < 64; d <<= 1) {
        #pragma unroll
        for (int r = 0; r < 8; ++r) v[r] = fmaxf(v[r], __shfl_xor(v[r], d));
    }
}
__device__ __forceinline__ void wave_reduce_min8i(int v[8]) {
    #pragma unroll
    for (int d = 1; d < 64; d <<= 1) {
        #pragma unroll
        for (int r = 0; r < 8; ++r) v[r] = min(v[r], __shfl_xor(v[r], d));
    }
}

__global__ __launch_bounds__(256, 2)
void actor_kernel(const float* __restrict__ state,
                  const float* __restrict__ amask,
                  const float* __restrict__ x_init,
                  const float* __restrict__ gum,
                  const float* __restrict__ b1,
                  const float* __restrict__ g1,
                  const float* __restrict__ be1,
                  const float* __restrict__ b2,
                  const float* __restrict__ g2,
                  const float* __restrict__ be2,
                  const float* __restrict__ b3,
                  const _Float16* __restrict__ T1h, const _Float16* __restrict__ T1l,
                  const _Float16* __restrict__ T2h, const _Float16* __restrict__ T2l,
                  const _Float16* __restrict__ T3h, const _Float16* __restrict__ T3l,
                  const float* __restrict__ w3cg,
                  float* __restrict__ out)
{
    // hA: h in f16 hi (dw 0..127) + lo (dw 128..255) per row m, stride 268 dw
    //     (12m mod 32 -> 8 bank groups -> all frag ops <=2-way conflicts).
    // xA: [x(0..128), t(129), 0(130..159)] hi (dw 0..79) + lo (dw 80..159), stride 172.
    // WB: weight k-tile, per n: hi dw 0..7, lo dw 8..15, pad to 20.
    __shared__ int    hA[32 * 268];
    __shared__ int    xA[32 * 172];
    __shared__ int    WB[256 * 20];
    __shared__ float  w3c[256];
    __shared__ float2 lnpart[4][32];
    __shared__ float2 lnstat[32];

    const int tid  = threadIdx.x;
    const int w    = tid >> 6;
    const int ln   = tid & 63;
    const int lh   = ln >> 5;       // k-half selector for frags
    const int l31  = ln & 31;
    const int row0 = blockIdx.x * M;

    const int n0 = 64 * w + l31;    // L1/L2 col for tile a
    const int n1 = n0 + 32;         // tile b
    const int n3 = 32 * w + l31;    // L3 col

    _Float16* hh = (_Float16*)hA;
    _Float16* xh = (_Float16*)xA;

    // ---------------- init staging ----------------
    {   // state -> hA (split f16, packed dword pairs)
        int m = tid & 31, kb = (tid >> 5) * 32;
        const float4* sp = (const float4*)(state + (size_t)(row0 + m) * SD + kb);
        int base = m * 268 + (kb >> 1);
        #pragma unroll
        for (int q = 0; q < 8; ++q) {
            float4 v = sp[q];
            _Float16 h0 = (_Float16)v.x, h1 = (_Float16)v.y,
                     h2 = (_Float16)v.z, h3 = (_Float16)v.w;
            *(v2h*)(hA + base + 2 * q)     = (v2h){h0, h1};
            *(v2h*)(hA + base + 2 * q + 1) = (v2h){h2, h3};
            *(v2h*)(hA + base + 128 + 2 * q)     =
                (v2h){(_Float16)((v.x - (float)h0) * LOSCALE),
                      (_Float16)((v.y - (float)h1) * LOSCALE)};
            *(v2h*)(hA + base + 128 + 2 * q + 1) =
                (v2h){(_Float16)((v.z - (float)h2) * LOSCALE),
                      (_Float16)((v.w - (float)h3) * LOSCALE)};
        }
    }
    {   // x_init (+t at 129, zeros 130..159) -> xA
        int m = tid & 31, c8 = tid >> 5;
        int k0 = c8 * 20;
        float vv[20];
        #pragma unroll
        for (int j = 0; j < 20; ++j) {
            int k = k0 + j;
            vv[j] = (k < AD) ? x_init[(size_t)(row0 + m) * AD + k]
                             : ((k == AD) ? (float)(NSTEP - 1) : 0.f);
        }
        int base = m * 172 + (k0 >> 1);
        #pragma unroll
        for (int j = 0; j < 10; ++j) {
            float a = vv[2 * j], b = vv[2 * j + 1];
            _Float16 ha = (_Float16)a, hb = (_Float16)b;
            *(v2h*)(xA + base + j)      = (v2h){ha, hb};
            *(v2h*)(xA + base + 80 + j) =
                (v2h){(_Float16)((a - (float)ha) * LOSCALE),
                      (_Float16)((b - (float)hb) * LOSCALE)};
        }
    }
    w3c[tid] = w3cg[tid];
    __syncthreads();

    // per-lane constants
    const float b1n0 = b1[n0], b1n1 = b1[n1];
    const float b2n0 = b2[n0], b2n1 = b2[n1];
    const float g1n0 = g1[n0], g1n1 = g1[n1];
    const float e1n0 = be1[n0], e1n1 = be1[n1];
    const float g2n0 = g2[n0], g2n1 = g2[n1];
    const float e2n0 = be2[n0], e2n1 = be2[n1];
    const float b3n  = b3[n3],  b3c  = b3[128];

    // x kept in fp32 registers (C-layout): xf[r] = x[m(r)][n3], x128 in lane i for row 8w+i
    float xf[16];
    #pragma unroll
    for (int r = 0; r < 16; ++r) {
        int m = (r & 3) + 8 * (r >> 2) + 4 * lh;
        xf[r] = x_init[(size_t)(row0 + m) * AD + n3];
    }
    float x128 = 0.f;
    if (ln < 8) x128 = x_init[(size_t)(row0 + 8 * w + ln) * AD + 128];

    // ---------------- weight-tile staging + GEMM engines ----------------
    int4 r0, r1, r2, r3;
    auto loadW256 = [&](const _Float16* gh, const _Float16* gl, int Kp, int kf) {
        const _Float16* ph = gh + (size_t)tid * Kp + kf;
        r0 = *(const int4*)ph;       r1 = *(const int4*)(ph + 8);
        const _Float16* pl = gl + (size_t)tid * Kp + kf;
        r2 = *(const int4*)pl;       r3 = *(const int4*)(pl + 8);
    };
    auto storeW256 = [&]() {
        *(int4*)(WB + tid * 20 + 0)  = r0;
        *(int4*)(WB + tid * 20 + 4)  = r1;
        *(int4*)(WB + tid * 20 + 8)  = r2;
        *(int4*)(WB + tid * 20 + 12) = r3;
    };
    // 2 n-tiles/wave, dual-acc split: c1 = hi*hi, c2 = hi*lo + lo*hi (lo pre-scaled 2^12)
    auto gemm256 = [&](const _Float16* gh, const _Float16* gl, int Kp, int kbase,
                       int ntile, const int* A, int astr, int aloff,
                       v16f& c1a, v16f& c2a, v16f& c1b, v16f& c2b) {
        loadW256(gh, gl, Kp, kbase);
        for (int t = 0; t < ntile; ++t) {
            storeW256();
            __syncthreads();
            if (t + 1 < ntile) loadW256(gh, gl, Kp, kbase + (t + 1) * 16);
            int adw = l31 * astr + t * 8 + lh * 4;
            v8h ahi = *(const v8h*)(A + adw);
            v8h alo = *(const v8h*)(A + adw + aloff);
            int wb0 = n0 * 20 + lh * 4;
            int wb1 = n1 * 20 + lh * 4;
            v8h bh0 = *(const v8h*)(WB + wb0);
            v8h bl0 = *(const v8h*)(WB + wb0 + 8);
            v8h bh1 = *(const v8h*)(WB + wb1);
            v8h bl1 = *(const v8h*)(WB + wb1 + 8);
            c1a = __builtin_amdgcn_mfma_f32_32x32x16_f16(ahi, bh0, c1a, 0, 0, 0);
            c2a = __builtin_amdgcn_mfma_f32_32x32x16_f16(ahi, bl0, c2a, 0, 0, 0);
            c2a = __builtin_amdgcn_mfma_f32_32x32x16_f16(alo, bh0, c2a, 0, 0, 0);
            c1b = __builtin_amdgcn_mfma_f32_32x32x16_f16(ahi, bh1, c1b, 0, 0, 0);
            c2b = __builtin_amdgcn_mfma_f32_32x32x16_f16(ahi, bl1, c2b, 0, 0, 0);
            c2b = __builtin_amdgcn_mfma_f32_32x32x16_f16(alo, bh1, c2b, 0, 0, 0);
            __syncthreads();
        }
    };
    auto loadW3 = [&](int kf) {
        int n = tid & 127;
        const _Float16* g = ((tid < 128) ? T3h : T3l) + (size_t)n * KP3 + kf;
        r0 = *(const int4*)g;  r1 = *(const int4*)(g + 8);
    };
    auto storeW3 = [&]() {
        int base = (tid & 127) * 20 + ((tid < 128) ? 0 : 8);
        *(int4*)(WB + base)     = r0;
        *(int4*)(WB + base + 4) = r1;
    };
    auto gemm_l3 = [&](v16f& c1, v16f& c2) {
        loadW3(0);
        for (int t = 0; t < 16; ++t) {
            storeW3();
            __syncthreads();
            if (t < 15) loadW3((t + 1) * 16);
            int adw = l31 * 268 + t * 8 + lh * 4;
            v8h ahi = *(const v8h*)(hA + adw);
            v8h alo = *(const v8h*)(hA + adw + 128);
            int wb = n3 * 20 + lh * 4;
            v8h bh = *(const v8h*)(WB + wb);
            v8h bl = *(const v8h*)(WB + wb + 8);
            c1 = __builtin_amdgcn_mfma_f32_32x32x16_f16(ahi, bh, c1, 0, 0, 0);
            c2 = __builtin_amdgcn_mfma_f32_32x32x16_f16(ahi, bl, c2, 0, 0, 0);
            c2 = __builtin_amdgcn_mfma_f32_32x32x16_f16(alo, bh, c2, 0, 0, 0);
            __syncthreads();
        }
    };

    // LayerNorm + ReLU on C-layout values, split-f16 store into hA.
    auto ln_store = [&](v16f va, v16f vb, float gn0v, float bn0v, float gn1v, float bn1v) {
        float sum[16], sq[16];
        #pragma unroll
        for (int r = 0; r < 16; ++r) {
            float t0 = va[r] + vb[r];
            float q0 = fmaf(va[r], va[r], vb[r] * vb[r]);
            #pragma unroll
            for (int d = 1; d < 32; d <<= 1) {
                t0 += __shfl_xor(t0, d);
                q0 += __shfl_xor(q0, d);
            }
            sum[r] = t0; sq[r] = q0;
        }
        if (l31 == 0) {
            #pragma unroll
            for (int r = 0; r < 16; ++r) {
                int m = (r & 3) + 8 * (r >> 2) + 4 * lh;
                lnpart[w][m] = make_float2(sum[r], sq[r]);
            }
        }
        __syncthreads();
        if (tid < 32) {
            float2 p0 = lnpart[0][tid], p1 = lnpart[1][tid],
                   p2 = lnpart[2][tid], p3 = lnpart[3][tid];
            float s = (p0.x + p1.x) + (p2.x + p3.x);
            float q = (p0.y + p1.y) + (p2.y + p3.y);
            float mean = s * (1.f / 256.f);
            float var  = q * (1.f / 256.f) - mean * mean;
            lnstat[tid] = make_float2(mean, rsqrtf(var + EPS_LN));
        }
        __syncthreads();
        #pragma unroll
        for (int r = 0; r < 16; ++r) {
            int m = (r & 3) + 8 * (r >> 2) + 4 * lh;
            float2 st = lnstat[m];
            float h0 = fmaxf((va[r] - st.x) * st.y * gn0v + bn0v, 0.f);
            float h1 = fmaxf((vb[r] - st.x) * st.y * gn1v + bn1v, 0.f);
            _Float16 a0 = (_Float16)h0, a1 = (_Float16)h1;
            hh[m * 536 + n0] = a0;
            hh[m * 536 + n1] = a1;
            hh[m * 536 + 256 + n0] = (_Float16)((h0 - (float)a0) * LOSCALE);
            hh[m * 536 + 256 + n1] = (_Float16)((h1 - (float)a1) * LOSCALE);
        }
    };

    // ---------------- pre = b1 + state @ W1[0:256,:] ----------------
    v16f prea, preb;
    {
        v16f c1a = vzero(), c2a = vzero(), c1b = vzero(), c2b = vzero();
        gemm256(T1h, T1l, KP1, 0, 16, hA, 268, 128, c1a, c2a, c1b, c2b);
        prea = c1a + LOINV * c2a + b1n0;
        preb = c1b + LOINV * c2b + b1n1;
    }

    // ---------------- diffusion steps ----------------
    for (int s = 0; s < NSTEP; ++s) {
        // layer 1: [x;t] @ W1[256:,:] + pre
        {
            v16f c1a = vzero(), c2a = vzero(), c1b = vzero(), c2b = vzero();
            gemm256(T1h, T1l, KP1, 256, 10, xA, 172, 80, c1a, c2a, c1b, c2b);
            v16f va = c1a + LOINV * c2a + prea;
            v16f vb = c1b + LOINV * c2b + preb;
            ln_store(va, vb, g1n0, e1n0, g1n1, e1n1);
        }
        // layer 2
        {
            v16f c1a = vzero(), c2a = vzero(), c1b = vzero(), c2b = vzero();
            gemm256(T2h, T2l, KP2, 0, 16, hA, 268, 128, c1a, c2a, c1b, c2b);
            v16f va = c1a + LOINV * c2a + b2n0;
            v16f vb = c1b + LOINV * c2b + b2n1;
            ln_store(va, vb, g2n0, e2n0, g2n1, e2n1);
        }
        // layer 3 cols 0..127 + x update
        {
            v16f c13 = vzero(), c23 = vzero();
            gemm_l3(c13, c23);
            v16f npv = c13 + LOINV * c23;
            #pragma unroll
            for (int r = 0; r < 16; ++r) {
                int m = (r & 3) + 8 * (r >> 2) + 4 * lh;
                float xn = xf[r] - 0.1f * (npv[r] + b3n);
                xf[r] = xn;
                _Float16 hx = (_Float16)xn;
                xh[m * 344 + n3] = hx;
                xh[m * 344 + 160 + n3] = (_Float16)((xn - (float)hx) * LOSCALE);
            }
            // col 128 (w3 last column) per wave-owned row
            float tn = (float)(NSTEP - 2 - s);
            #pragma unroll
            for (int i = 0; i < 8; ++i) {
                int m = 8 * w + i;
                float p = 0.f;
                #pragma unroll
                for (int q = 0; q < 4; ++q) {
                    int k = ln + 64 * q;
                    float h = (float)hh[m * 536 + k] + LOINV * (float)hh[m * 536 + 256 + k];
                    p = fmaf(h, w3c[k], p);
                }
                #pragma unroll
                for (int d = 1; d < 64; d <<= 1) p += __shfl_xor(p, d);
                if (ln == i) {
                    x128 = x128 - 0.1f * (p + b3c);
                    _Float16 hx = (_Float16)x128;
                    xh[m * 344 + 128] = hx;
                    xh[m * 344 + 160 + 128] = (_Float16)((x128 - (float)hx) * LOSCALE);
                    xh[m * 344 + 129] = (_Float16)tn;
                    xh[m * 344 + 160 + 129] = (_Float16)0.f;
                }
            }
            __syncthreads();
        }
    }

    // ---------------- finale ----------------
    {
        float xv[16];
        #pragma unroll
        for (int c = 0; c < 2; ++c) {
            int col = 2 * ln + c;   // 0..127
            #pragma unroll
            for (int r = 0; r < 8; ++r) {
                int m = 8 * w + r;
                xv[r * 2 + c] = (float)xh[m * 344 + col]
                              + LOINV * (float)xh[m * 344 + 160 + col];
            }
        }
        float lg[16];
        #pragma unroll
        for (int r = 0; r < 8; ++r) {
            size_t grow = (size_t)(row0 + 8 * w + r);
            float2 mv = *(const float2*)&amask[grow * 128 + 2 * ln];
            float2 gv = *(const float2*)&gum  [grow * 128 + 2 * ln];
            lg[r * 2 + 0] = xv[r * 2 + 0] + (1.f - mv.x) * -1e9f + gv.x;
            lg[r * 2 + 1] = xv[r * 2 + 1] + (1.f - mv.y) * -1e9f + gv.y;
        }
        float mx[8];
        #pragma unroll
        for (int r = 0; r < 8; ++r) mx[r] = fmaxf(lg[r * 2], lg[r * 2 + 1]);
        wave_reduce_max8(mx);
        float es[16], sum[8];
        #pragma unroll
        for (int r = 0; r < 8; ++r) {
            es[r * 2 + 0] = expf(lg[r * 2 + 0] - mx[r]);
            es[r * 2 + 1] = expf(lg[r * 2 + 1] - mx[r]);
            sum[r] = es[r * 2 + 0] + es[r * 2 + 1];
        }
        wave_reduce_add8(sum);
        float soft[16], sm[8];
        #pragma unroll
        for (int r = 0; r < 8; ++r) {
            soft[r * 2 + 0] = es[r * 2 + 0] / sum[r];
            soft[r * 2 + 1] = es[r * 2 + 1] / sum[r];
            sm[r] = fmaxf(soft[r * 2 + 0], soft[r * 2 + 1]);
        }
        wave_reduce_max8(sm);
        int idx[8];
        #pragma unroll
        for (int r = 0; r < 8; ++r) {
            idx[r] = (soft[r * 2 + 0] == sm[r]) ? (2 * ln)
                   : ((soft[r * 2 + 1] == sm[r]) ? (2 * ln + 1) : 0x7fffffff);
        }
        wave_reduce_min8i(idx);
        #pragma unroll
        for (int r = 0; r < 8; ++r) {
            size_t grow = (size_t)(row0 + 8 * w + r);
            float* orow = out + grow * AD;
            float h0 = (2 * ln + 0 == idx[r]) ? 1.f : 0.f;
            float h1 = (2 * ln + 1 == idx[r]) ? 1.f : 0.f;
            orow[2 * ln + 0] = h0 + soft[r * 2 + 0] - soft[r * 2 + 0];
            orow[2 * ln + 1] = h1 + soft[r * 2 + 1] - soft[r * 2 + 1];
        }
        if (ln == 0) {
            #pragma unroll
            for (int r = 0; r < 8; ++r) {
                int m = 8 * w + r;
                float sv = (float)xh[m * 344 + 128] + LOINV * (float)xh[m * 344 + 160 + 128];
                out[(size_t)(row0 + m) * AD + 128] = tanhf(sv);
            }
        }
    }
}

extern "C" void kernel_launch(void* const* d_in, const int* in_sizes, int n_in,
                              void* d_out, int out_size, void* d_ws, size_t ws_size,
                              hipStream_t stream) {
    const float* state  = (const float*)d_in[0];
    const float* amask  = (const float*)d_in[1];
    const float* x_init = (const float*)d_in[2];
    const float* gum    = (const float*)d_in[3];
    const float* W1     = (const float*)d_in[4];
    const float* b1     = (const float*)d_in[5];
    const float* g1     = (const float*)d_in[6];
    const float* be1    = (const float*)d_in[7];
    const float* W2     = (const float*)d_in[8];
    const float* b2     = (const float*)d_in[9];
    const float* g2     = (const float*)d_in[10];
    const float* be2    = (const float*)d_in[11];
    const float* W3     = (const float*)d_in[12];
    const float* b3     = (const float*)d_in[13];
    float* out = (float*)d_out;
    char*  ws  = (char*)d_ws;   // ~820 KB used

    hipLaunchKernelGGL(repack, dim3(256), dim3(256), 0, stream, W1, W2, W3, ws);
    hipLaunchKernelGGL(actor_kernel, dim3(BATCH / M), dim3(256), 0, stream,
                       state, amask, x_init, gum,
                       b1, g1, be1, b2, g2, be2, b3,
                       (const _Float16*)(ws + T1H_OFF), (const _Float16*)(ws + T1L_OFF),
                       (const _Float16*)(ws + T2H_OFF), (const _Float16*)(ws + T2L_OFF),
                       (const _Float16*)(ws + T3H_OFF), (const _Float16*)(ws + T3L_OFF),
                       (const float*)(ws + W3C_OFF), out);
}

// Round 5
// 5934.214 us; speedup vs baseline: 2.0778x; 2.0778x over previous
//
#include <hip/hip_runtime.h>
#include <math.h>

#define BATCH  65536
#define SD     256
#define AD     129
#define HID    256
#define NSTEP  30
#define EPS_LN 1e-5f

typedef _Float16 v8h  __attribute__((ext_vector_type(8)));
typedef _Float16 v2h  __attribute__((ext_vector_type(2)));
typedef float    v16f __attribute__((ext_vector_type(16)));

#define LOSCALE 4096.0f
#define LOINV   (1.0f/4096.0f)
#define MFMA(a,b,c) __builtin_amdgcn_mfma_f32_32x32x16_f16(a,b,c,0,0,0)

// d_ws layout (bytes) — transposed, fp16-split weights (same as round 4). ~820 KB.
#define T1H_OFF 0
#define T1L_OFF 212992
#define T2H_OFF 425984
#define T2L_OFF 557056
#define T3H_OFF 688128
#define T3L_OFF 753664
#define W3C_OFF 819200
#define KP1 416
#define KP2 256
#define KP3 256

__global__ __launch_bounds__(256)
void repack(const float* __restrict__ W1, const float* __restrict__ W2,
            const float* __restrict__ W3, char* __restrict__ ws)
{
    _Float16* t1h = (_Float16*)(ws + T1H_OFF);
    _Float16* t1l = (_Float16*)(ws + T1L_OFF);
    _Float16* t2h = (_Float16*)(ws + T2H_OFF);
    _Float16* t2l = (_Float16*)(ws + T2L_OFF);
    _Float16* t3h = (_Float16*)(ws + T3H_OFF);
    _Float16* t3l = (_Float16*)(ws + T3L_OFF);
    float*    w3c = (float*)(ws + W3C_OFF);
    const int n = blockIdx.x;
    for (int k = threadIdx.x; k < KP1; k += 256) {
        float v = (k < 386) ? W1[(size_t)k * HID + n] : 0.f;
        _Float16 h = (_Float16)v;
        t1h[(size_t)n * KP1 + k] = h;
        t1l[(size_t)n * KP1 + k] = (_Float16)((v - (float)h) * LOSCALE);
    }
    {
        int k = threadIdx.x;
        float v = W2[(size_t)k * HID + n];
        _Float16 h = (_Float16)v;
        t2h[(size_t)n * KP2 + k] = h;
        t2l[(size_t)n * KP2 + k] = (_Float16)((v - (float)h) * LOSCALE);
    }
    if (n < 128) {
        int k = threadIdx.x;
        float v = W3[(size_t)k * AD + n];
        _Float16 h = (_Float16)v;
        t3h[(size_t)n * KP3 + k] = h;
        t3l[(size_t)n * KP3 + k] = (_Float16)((v - (float)h) * LOSCALE);
    }
    if (n == 0) w3c[threadIdx.x] = W3[(size_t)threadIdx.x * AD + 128];
}

__device__ __forceinline__ v16f vzero() {
    v16f z;
    #pragma unroll
    for (int i = 0; i < 16; ++i) z[i] = 0.f;
    return z;
}
__device__ __forceinline__ void wave_reduce_add8(float v[8]) {
    #pragma unroll
    for (int d = 1; d < 64; d <<= 1) {
        #pragma unroll
        for (int r = 0; r < 8; ++r) v[r] += __shfl_xor(v[r], d);
    }
}
__device__ __forceinline__ void wave_reduce_max8(float v[8]) {
    #pragma unroll
    for (int d = 1; d < 64; d <<= 1) {
        #pragma unroll
        for (int r = 0; r < 8; ++r) v[r] = fmaxf(v[r], __shfl_xor(v[r], d));
    }
}
__device__ __forceinline__ void wave_reduce_min8i(int v[8]) {
    #pragma unroll
    for (int d = 1; d < 64; d <<= 1) {
        #pragma unroll
        for (int r = 0; r < 8; ++r) v[r] = min(v[r], __shfl_xor(v[r], d));
    }
}

// M=64 rows/block, 512 threads = 8 waves: wave = (mh = w>>2) m-half x (nq = w&3) n-quarter.
// Weights: B-fragments register-direct from global (no LDS staging, no GEMM barriers).
// Activations: split-f16 in LDS (hA stride 268 dw; xA stride 148 dw, K=144 padded).
__global__ __launch_bounds__(512, 2)
void actor_kernel(const float* __restrict__ state,
                  const float* __restrict__ amask,
                  const float* __restrict__ x_init,
                  const float* __restrict__ gum,
                  const float* __restrict__ b1,
                  const float* __restrict__ g1,
                  const float* __restrict__ be1,
                  const float* __restrict__ b2,
                  const float* __restrict__ g2,
                  const float* __restrict__ be2,
                  const float* __restrict__ b3,
                  const _Float16* __restrict__ T1h, const _Float16* __restrict__ T1l,
                  const _Float16* __restrict__ T2h, const _Float16* __restrict__ T2l,
                  const _Float16* __restrict__ T3h, const _Float16* __restrict__ T3l,
                  const float* __restrict__ w3cg,
                  float* __restrict__ out)
{
    __shared__ int    hA[64 * 268];   // 68.6 KB: hi f16 dw 0..127, lo dw 128..255 per row
    __shared__ int    xA[64 * 148];   // 37.9 KB: hi dw 0..71 (144 f16), lo dw 72..143
    __shared__ float  w3c[256];
    __shared__ float2 lnpart[4][64];

    const int tid  = threadIdx.x;
    const int w    = tid >> 6;
    const int ln   = tid & 63;
    const int lh   = ln >> 5;
    const int l31  = ln & 31;
    const int mh   = w >> 2;
    const int nq   = w & 3;
    const int n0   = 64 * nq + l31;
    const int n1   = n0 + 32;
    const int n3   = 32 * nq + l31;
    const int row0 = blockIdx.x * 64;

    _Float16* hh = (_Float16*)hA;
    _Float16* xh = (_Float16*)xA;

    int mr[16];
    #pragma unroll
    for (int r = 0; r < 16; ++r) mr[r] = 32 * mh + (r & 3) + 8 * (r >> 2) + 4 * lh;

    // ---------------- init staging ----------------
    {   // state -> hA split
        int m = tid & 63, kb = (tid >> 6) * 32;
        const float4* sp = (const float4*)(state + (size_t)(row0 + m) * SD + kb);
        int base = m * 268 + (kb >> 1);
        #pragma unroll
        for (int q = 0; q < 8; ++q) {
            float4 v = sp[q];
            _Float16 h0 = (_Float16)v.x, h1 = (_Float16)v.y,
                     h2 = (_Float16)v.z, h3 = (_Float16)v.w;
            *(v2h*)(hA + base + 2 * q)     = (v2h){h0, h1};
            *(v2h*)(hA + base + 2 * q + 1) = (v2h){h2, h3};
            *(v2h*)(hA + base + 128 + 2 * q) =
                (v2h){(_Float16)((v.x - (float)h0) * LOSCALE),
                      (_Float16)((v.y - (float)h1) * LOSCALE)};
            *(v2h*)(hA + base + 128 + 2 * q + 1) =
                (v2h){(_Float16)((v.z - (float)h2) * LOSCALE),
                      (_Float16)((v.w - (float)h3) * LOSCALE)};
        }
    }
    {   // x_init (+t at 129, zeros 130..143) -> xA split
        int m = tid & 63, k0 = (tid >> 6) * 18;
        float vv[18];
        #pragma unroll
        for (int j = 0; j < 18; ++j) {
            int k = k0 + j;
            vv[j] = (k < AD) ? x_init[(size_t)(row0 + m) * AD + k]
                             : ((k == AD) ? (float)(NSTEP - 1) : 0.f);
        }
        int base = m * 148 + (k0 >> 1);
        #pragma unroll
        for (int j = 0; j < 9; ++j) {
            float a = vv[2 * j], b = vv[2 * j + 1];
            _Float16 ha = (_Float16)a, hb = (_Float16)b;
            *(v2h*)(xA + base + j)      = (v2h){ha, hb};
            *(v2h*)(xA + base + 72 + j) =
                (v2h){(_Float16)((a - (float)ha) * LOSCALE),
                      (_Float16)((b - (float)hb) * LOSCALE)};
        }
    }
    if (tid < 256) w3c[tid] = w3cg[tid];
    __syncthreads();

    const float b1n0 = b1[n0], b1n1 = b1[n1];
    const float b2n0 = b2[n0], b2n1 = b2[n1];
    const float g1n0 = g1[n0], g1n1 = g1[n1];
    const float e1n0 = be1[n0], e1n1 = be1[n1];
    const float g2n0 = g2[n0], g2n1 = g2[n1];
    const float e2n0 = be2[n0], e2n1 = be2[n1];
    const float b3n  = b3[n3],  b3c  = b3[128];

    // x in fp32 registers (C-layout col n3), col 128 in lane i (i<8) per wave-row
    float xf[16];
    #pragma unroll
    for (int r = 0; r < 16; ++r)
        xf[r] = x_init[(size_t)(row0 + mr[r]) * AD + n3];
    float x128 = (ln < 8) ? x_init[(size_t)(row0 + 8 * w + ln) * AD + 128] : 0.f;

    // ---------------- GEMM engines: register-direct B, barrier-free ----------------
    auto gemm2 = [&](const _Float16* Th, const _Float16* Tl, int Kp, int kbase, int ntile,
                     const int* Ab, int astr, int aloff,
                     v16f& c1a, v16f& c2a, v16f& c1b, v16f& c2b) {
        const _Float16* ph0 = Th + (size_t)n0 * Kp + kbase + lh * 8;
        const _Float16* pl0 = Tl + (size_t)n0 * Kp + kbase + lh * 8;
        const _Float16* ph1 = Th + (size_t)n1 * Kp + kbase + lh * 8;
        const _Float16* pl1 = Tl + (size_t)n1 * Kp + kbase + lh * 8;
        const int abase = (32 * mh + l31) * astr + lh * 4;
        #pragma unroll 4
        for (int t = 0; t < ntile; ++t) {
            v8h bh0 = *(const v8h*)(ph0 + 16 * t);
            v8h bl0 = *(const v8h*)(pl0 + 16 * t);
            v8h bh1 = *(const v8h*)(ph1 + 16 * t);
            v8h bl1 = *(const v8h*)(pl1 + 16 * t);
            v8h ahi = *(const v8h*)(Ab + abase + 8 * t);
            v8h alo = *(const v8h*)(Ab + abase + aloff + 8 * t);
            c1a = MFMA(ahi, bh0, c1a);
            c2a = MFMA(ahi, bl0, c2a);
            c2a = MFMA(alo, bh0, c2a);
            c1b = MFMA(ahi, bh1, c1b);
            c2b = MFMA(ahi, bl1, c2b);
            c2b = MFMA(alo, bh1, c2b);
        }
    };
    auto gemm_l3 = [&](v16f& c1, v16f& c2) {
        const _Float16* ph = T3h + (size_t)n3 * KP3 + lh * 8;
        const _Float16* pl = T3l + (size_t)n3 * KP3 + lh * 8;
        const int abase = (32 * mh + l31) * 268 + lh * 4;
        #pragma unroll 4
        for (int t = 0; t < 16; ++t) {
            v8h bh = *(const v8h*)(ph + 16 * t);
            v8h bl = *(const v8h*)(pl + 16 * t);
            v8h ahi = *(const v8h*)(hA + abase + 8 * t);
            v8h alo = *(const v8h*)(hA + abase + 128 + 8 * t);
            c1 = MFMA(ahi, bh, c1);
            c2 = MFMA(ahi, bl, c2);
            c2 = MFMA(alo, bh, c2);
        }
    };

    // LN + ReLU: wave-local 32-lane partials -> lnpart -> barrier -> per-lane stats -> hA
    auto ln_store = [&](v16f va, v16f vb, float gn0v, float bn0v, float gn1v, float bn1v) {
        float sum[16], sq[16];
        #pragma unroll
        for (int r = 0; r < 16; ++r) {
            float t0 = va[r] + vb[r];
            float q0 = fmaf(va[r], va[r], vb[r] * vb[r]);
            #pragma unroll
            for (int d = 1; d < 32; d <<= 1) {
                t0 += __shfl_xor(t0, d);
                q0 += __shfl_xor(q0, d);
            }
            sum[r] = t0; sq[r] = q0;
        }
        if (l31 == 0) {
            #pragma unroll
            for (int r = 0; r < 16; ++r)
                lnpart[nq][mr[r]] = make_float2(sum[r], sq[r]);
        }
        __syncthreads();   // also guarantees all waves done reading hA/xA in the GEMM
        #pragma unroll
        for (int r = 0; r < 16; ++r) {
            int m = mr[r];
            float2 p0 = lnpart[0][m], p1 = lnpart[1][m],
                   p2 = lnpart[2][m], p3 = lnpart[3][m];
            float sm = (p0.x + p1.x) + (p2.x + p3.x);
            float qm = (p0.y + p1.y) + (p2.y + p3.y);
            float mean = sm * (1.f / 256.f);
            float rstd = rsqrtf(qm * (1.f / 256.f) - mean * mean + EPS_LN);
            float h0 = fmaxf((va[r] - mean) * rstd * gn0v + bn0v, 0.f);
            float h1 = fmaxf((vb[r] - mean) * rstd * gn1v + bn1v, 0.f);
            _Float16 a0 = (_Float16)h0, a1 = (_Float16)h1;
            hh[m * 536 + n0] = a0;
            hh[m * 536 + n1] = a1;
            hh[m * 536 + 256 + n0] = (_Float16)((h0 - (float)a0) * LOSCALE);
            hh[m * 536 + 256 + n1] = (_Float16)((h1 - (float)a1) * LOSCALE);
        }
        __syncthreads();   // hA (and lnpart read-before-overwrite) complete
    };

    // ---------------- pre = b1 + state @ W1[0:256,:] ----------------
    v16f prea, preb;
    {
        v16f c1a = vzero(), c2a = vzero(), c1b = vzero(), c2b = vzero();
        gemm2(T1h, T1l, KP1, 0, 16, hA, 268, 128, c1a, c2a, c1b, c2b);
        prea = c1a + LOINV * c2a + b1n0;
        preb = c1b + LOINV * c2b + b1n1;
    }

    // ---------------- diffusion steps ----------------
    #pragma unroll 1
    for (int s = 0; s < NSTEP; ++s) {
        {   // layer 1: [x;t] @ W1[256:,:] + pre  (K=144 padded)
            v16f c1a = vzero(), c2a = vzero(), c1b = vzero(), c2b = vzero();
            gemm2(T1h, T1l, KP1, 256, 9, xA, 148, 72, c1a, c2a, c1b, c2b);
            v16f va = c1a + LOINV * c2a + prea;
            v16f vb = c1b + LOINV * c2b + preb;
            ln_store(va, vb, g1n0, e1n0, g1n1, e1n1);
        }
        {   // layer 2
            v16f c1a = vzero(), c2a = vzero(), c1b = vzero(), c2b = vzero();
            gemm2(T2h, T2l, KP2, 0, 16, hA, 268, 128, c1a, c2a, c1b, c2b);
            v16f va = c1a + LOINV * c2a + b2n0;
            v16f vb = c1b + LOINV * c2b + b2n1;
            ln_store(va, vb, g2n0, e2n0, g2n1, e2n1);
        }
        {   // layer 3 + x update
            v16f c13 = vzero(), c23 = vzero();
            gemm_l3(c13, c23);
            v16f npv = c13 + LOINV * c23;
            #pragma unroll
            for (int r = 0; r < 16; ++r) {
                int m = mr[r];
                float xn = xf[r] - 0.1f * (npv[r] + b3n);
                xf[r] = xn;
                _Float16 hx = (_Float16)xn;
                xh[m * 296 + n3] = hx;
                xh[m * 296 + 144 + n3] = (_Float16)((xn - (float)hx) * LOSCALE);
            }
            // col 128: wave w handles rows 8w..8w+7 (k-split over 64 lanes)
            float tn = (float)(NSTEP - 2 - s);
            #pragma unroll
            for (int i = 0; i < 8; ++i) {
                int m = 8 * w + i;
                float p = 0.f;
                #pragma unroll
                for (int q = 0; q < 4; ++q) {
                    int k = ln + 64 * q;
                    float h = (float)hh[m * 536 + k] + LOINV * (float)hh[m * 536 + 256 + k];
                    p = fmaf(h, w3c[k], p);
                }
                #pragma unroll
                for (int d = 1; d < 64; d <<= 1) p += __shfl_xor(p, d);
                if (ln == i) {
                    x128 = x128 - 0.1f * (p + b3c);
                    _Float16 hx = (_Float16)x128;
                    xh[m * 296 + 128] = hx;
                    xh[m * 296 + 144 + 128] = (_Float16)((x128 - (float)hx) * LOSCALE);
                    xh[m * 296 + 129] = (_Float16)tn;
                    xh[m * 296 + 144 + 129] = (_Float16)0.f;
                }
            }
            __syncthreads();
        }
    }

    // ---------------- finale: masked gumbel softmax + tanh ----------------
    {
        float xv[16];
        #pragma unroll
        for (int c = 0; c < 2; ++c) {
            int col = 2 * ln + c;
            #pragma unroll
            for (int r = 0; r < 8; ++r) {
                int m = 8 * w + r;
                xv[r * 2 + c] = (float)xh[m * 296 + col]
                              + LOINV * (float)xh[m * 296 + 144 + col];
            }
        }
        float lg[16];
        #pragma unroll
        for (int r = 0; r < 8; ++r) {
            size_t grow = (size_t)(row0 + 8 * w + r);
            float2 mv = *(const float2*)&amask[grow * 128 + 2 * ln];
            float2 gv = *(const float2*)&gum  [grow * 128 + 2 * ln];
            lg[r * 2 + 0] = xv[r * 2 + 0] + (1.f - mv.x) * -1e9f + gv.x;
            lg[r * 2 + 1] = xv[r * 2 + 1] + (1.f - mv.y) * -1e9f + gv.y;
        }
        float mx[8];
        #pragma unroll
        for (int r = 0; r < 8; ++r) mx[r] = fmaxf(lg[r * 2], lg[r * 2 + 1]);
        wave_reduce_max8(mx);
        float es[16], sum[8];
        #pragma unroll
        for (int r = 0; r < 8; ++r) {
            es[r * 2 + 0] = expf(lg[r * 2 + 0] - mx[r]);
            es[r * 2 + 1] = expf(lg[r * 2 + 1] - mx[r]);
            sum[r] = es[r * 2 + 0] + es[r * 2 + 1];
        }
        wave_reduce_add8(sum);
        float soft[16], sm[8];
        #pragma unroll
        for (int r = 0; r < 8; ++r) {
            soft[r * 2 + 0] = es[r * 2 + 0] / sum[r];
            soft[r * 2 + 1] = es[r * 2 + 1] / sum[r];
            sm[r] = fmaxf(soft[r * 2 + 0], soft[r * 2 + 1]);
        }
        wave_reduce_max8(sm);
        int idx[8];
        #pragma unroll
        for (int r = 0; r < 8; ++r) {
            idx[r] = (soft[r * 2 + 0] == sm[r]) ? (2 * ln)
                   : ((soft[r * 2 + 1] == sm[r]) ? (2 * ln + 1) : 0x7fffffff);
        }
        wave_reduce_min8i(idx);
        #pragma unroll
        for (int r = 0; r < 8; ++r) {
            size_t grow = (size_t)(row0 + 8 * w + r);
            float* orow = out + grow * AD;
            float h0 = (2 * ln + 0 == idx[r]) ? 1.f : 0.f;
            float h1 = (2 * ln + 1 == idx[r]) ? 1.f : 0.f;
            orow[2 * ln + 0] = h0 + soft[r * 2 + 0] - soft[r * 2 + 0];
            orow[2 * ln + 1] = h1 + soft[r * 2 + 1] - soft[r * 2 + 1];
        }
        if (ln == 0) {
            #pragma unroll
            for (int r = 0; r < 8; ++r) {
                int m = 8 * w + r;
                float sv = (float)xh[m * 296 + 128] + LOINV * (float)xh[m * 296 + 144 + 128];
                out[(size_t)(row0 + m) * AD + 128] = tanhf(sv);
            }
        }
    }
}

extern "C" void kernel_launch(void* const* d_in, const int* in_sizes, int n_in,
                              void* d_out, int out_size, void* d_ws, size_t ws_size,
                              hipStream_t stream) {
    const float* state  = (const float*)d_in[0];
    const float* amask  = (const float*)d_in[1];
    const float* x_init = (const float*)d_in[2];
    const float* gum    = (const float*)d_in[3];
    const float* W1     = (const float*)d_in[4];
    const float* b1     = (const float*)d_in[5];
    const float* g1     = (const float*)d_in[6];
    const float* be1    = (const float*)d_in[7];
    const float* W2     = (const float*)d_in[8];
    const float* b2     = (const float*)d_in[9];
    const float* g2     = (const float*)d_in[10];
    const float* be2    = (const float*)d_in[11];
    const float* W3     = (const float*)d_in[12];
    const float* b3     = (const float*)d_in[13];
    float* out = (float*)d_out;
    char*  ws  = (char*)d_ws;

    hipLaunchKernelGGL(repack, dim3(256), dim3(256), 0, stream, W1, W2, W3, ws);
    hipLaunchKernelGGL(actor_kernel, dim3(BATCH / 64), dim3(512), 0, stream,
                       state, amask, x_init, gum,
                       b1, g1, be1, b2, g2, be2, b3,
                       (const _Float16*)(ws + T1H_OFF), (const _Float16*)(ws + T1L_OFF),
                       (const _Float16*)(ws + T2H_OFF), (const _Float16*)(ws + T2L_OFF),
                       (const _Float16*)(ws + T3H_OFF), (const _Float16*)(ws + T3L_OFF),
                       (const float*)(ws + W3C_OFF), out);
}